// Round 4
// baseline (311.459 us; speedup 1.0000x reference)
//
#include <hip/hip_runtime.h>
#include <math.h>

#define TOKENS 16384
#define DIM    2048
#define NE     64
#define BT     32          // tokens per block
#define TW     8           // tokens per wave
#define KC     32          // k per phase
#define HALFK  (DIM / 2)   // k-split 2: each wave owns 1024 k
#define NPH    (HALFK / KC)// 32 phases
#define WSTR   36          // LDS w row stride in floats (144 B: 16B-aligned, balanced banks)
#define WTILE  (NE * WSTR) // 2304 floats per (buf,half) tile

// One fused kernel. Wave = 64 lanes <-> 64 experts. Lane e accumulates
// logits[t][e] for 8 tokens over its k-half. x is read via wave-uniform
// addresses (scalar path); W rows ([e][k] already!) staged per-phase in LDS.
__global__ __launch_bounds__(512, 4) void router_kernel(const float* __restrict__ x,
                                                        const float* __restrict__ W,
                                                        const float* __restrict__ b,
                                                        float* __restrict__ out) {
    __shared__ __align__(16) float lds[2 * 2 * WTILE];   // 36 KB

    const int tid = threadIdx.x;

    // ---- staging ids (per-thread) ----
    const int sh  = tid >> 8;          // staging half 0/1
    const int ts  = tid & 255;
    const int e_s = ts >> 2;           // expert row this thread stages
    const int kq  = (ts & 3) * 8;      // 8 floats within the 32-float chunk

    // ---- compute ids (wave-uniform where it matters) ----
    const int wid  = __builtin_amdgcn_readfirstlane(tid >> 6);  // 0..7
    const int h    = wid & 1;          // k-half
    const int tg   = wid >> 1;         // token group 0..3
    const int lane = tid & 63;         // = expert index
    const int t0   = blockIdx.x * BT;

    const float* __restrict__ gw = W + (size_t)e_s * DIM + sh * HALFK + kq;
    const float* __restrict__ xbase = x + (size_t)(t0 + tg * TW) * DIM + h * HALFK;

    float4 acc[TW];
    #pragma unroll
    for (int t = 0; t < TW; ++t) acc[t] = make_float4(0.f, 0.f, 0.f, 0.f);

    // ---- prologue: stage phase 0 ----
    {
        float4 g0 = *(const float4*)(gw);
        float4 g1 = *(const float4*)(gw + 4);
        float* d = &lds[(0 * 2 + sh) * WTILE + e_s * WSTR + kq];
        *(float4*)(d)     = g0;
        *(float4*)(d + 4) = g1;
    }
    __syncthreads();

    for (int kc = 0; kc < NPH; ++kc) {
        const int cur = kc & 1;

        // issue next phase's global W loads early (VMEM in flight over compute)
        float4 g0, g1;
        if (kc + 1 < NPH) {
            const float* gsrc = gw + (kc + 1) * KC;
            g0 = *(const float4*)(gsrc);
            g1 = *(const float4*)(gsrc + 4);
        }

        // w fragment: lane's expert row, 32 k values -> 8 b128 reads
        float4 wreg[8];
        {
            const float* wr = &lds[(cur * 2 + h) * WTILE + lane * WSTR];
            #pragma unroll
            for (int j = 0; j < 8; ++j) wreg[j] = *(const float4*)(wr + 4 * j);
        }

        // tokens: x via wave-uniform loads (scalar path), 32 FMAs each
        #pragma unroll
        for (int t = 0; t < TW; ++t) {
            const float4* __restrict__ xp =
                (const float4*)(xbase + (size_t)t * DIM + kc * KC);
            float4 a = acc[t];
            #pragma unroll
            for (int j = 0; j < 8; ++j) {
                const float4 xv = xp[j];
                a.x += xv.x * wreg[j].x;
                a.y += xv.y * wreg[j].y;
                a.z += xv.z * wreg[j].z;
                a.w += xv.w * wreg[j].w;
            }
            acc[t] = a;
        }

        // store next phase's W tile into the other buffer
        if (kc + 1 < NPH) {
            float* d = &lds[((cur ^ 1) * 2 + sh) * WTILE + e_s * WSTR + kq];
            *(float4*)(d)     = g0;
            *(float4*)(d + 4) = g1;
        }
        __syncthreads();
    }

    // ---- reduce 4 k-partials -> per-token logit (this wave's k-half) ----
    float lg[TW];
    #pragma unroll
    for (int t = 0; t < TW; ++t)
        lg[t] = (acc[t].x + acc[t].y) + (acc[t].z + acc[t].w);

    // ---- combine k-halves via LDS (buf0 region is dead: last phase read buf1) ----
    if (h == 1) {
        #pragma unroll
        for (int t = 0; t < TW; ++t)
            lds[tg * (TW * NE) + t * NE + lane] = lg[t];
    }
    __syncthreads();

    if (h == 0) {
        const float bv = b[lane];
        float* logits_out = out + (size_t)TOKENS * 4;
        float* idxf = out + (size_t)TOKENS * 2;
        #pragma unroll
        for (int t = 0; t < TW; ++t) {
            const float v = lg[t] + lds[tg * (TW * NE) + t * NE + lane] + bv;
            const int tok = t0 + tg * TW + t;
            logits_out[(size_t)tok * NE + lane] = v;   // coalesced 256 B/wave

            // top-2 over the 64 lanes (lane = expert), smallest-index tie-break
            float v1 = v; int i1 = lane;
            #pragma unroll
            for (int off = 32; off >= 1; off >>= 1) {
                float ov = __shfl_xor(v1, off, 64);
                int   oi = __shfl_xor(i1, off, 64);
                if (ov > v1 || (ov == v1 && oi < i1)) { v1 = ov; i1 = oi; }
            }
            float vm = (lane == i1) ? -INFINITY : v;
            float v2 = vm; int i2 = lane;
            #pragma unroll
            for (int off = 32; off >= 1; off >>= 1) {
                float ov = __shfl_xor(v2, off, 64);
                int   oi = __shfl_xor(i2, off, 64);
                if (ov > v2 || (ov == v2 && oi < i2)) { v2 = ov; i2 = oi; }
            }

            if (lane == 0) {
                float e1 = expf(v2 - v1);          // v1 >= v2: stable
                float sden = 1.0f + e1;
                *(float2*)&out[(size_t)tok * 2] = make_float2(1.0f / sden, e1 / sden);
                *(float2*)&idxf[(size_t)tok * 2] = make_float2((float)i1, (float)i2);
            }
        }
    }
}

extern "C" void kernel_launch(void* const* d_in, const int* in_sizes, int n_in,
                              void* d_out, int out_size, void* d_ws, size_t ws_size,
                              hipStream_t stream) {
    const float* x = (const float*)d_in[0];
    const float* W = (const float*)d_in[1];   // [64][2048] row-major == [e][k], used directly
    const float* b = (const float*)d_in[2];
    float* out = (float*)d_out;

    router_kernel<<<TOKENS / BT, 512, 0, stream>>>(x, W, b, out);
}

// Round 5
// 217.323 us; speedup vs baseline: 1.4332x; 1.4332x over previous
//
#include <hip/hip_runtime.h>
#include <math.h>

#define TOKENS 16384
#define DIM    2048
#define NE     64
#define TB     64          // tokens per block
#define NPH    16          // phases
#define KPH    64          // k per phase per k-group
#define HALFK  1024

typedef _Float16 f16x8 __attribute__((ext_vector_type(8)));
typedef _Float16 f16x4 __attribute__((ext_vector_type(4)));
typedef float    f32x16 __attribute__((ext_vector_type(16)));

// LDS byte map (128 KB, double buffered):
//   X(buf,kg,spl) = buf*65536 + (kg*2+spl)*8192          (64 rows x 128 B)
//   W(buf,kg,spl) = buf*65536 + 32768 + (kg*2+spl)*8192  (64 rows x 128 B)
// Rows are 64 f16 = 128 B, XOR-swizzled in 16-B octets: phys = oct ^ sw(row).
__device__ __forceinline__ int sw(int r) { return (r ^ (r >> 3)) & 7; }

// ---------- Kernel A: split W fp32 -> wh/wl f16 pair in workspace ----------
__global__ __launch_bounds__(256) void wsplit_kernel(const float* __restrict__ W,
                                                     _Float16* __restrict__ wh,
                                                     _Float16* __restrict__ wl) {
    const int i = (blockIdx.x * 256 + threadIdx.x) * 4;
    float4 v = *(const float4*)&W[i];
    const float* pv = (const float*)&v;
    f16x4 h, l;
    #pragma unroll
    for (int k = 0; k < 4; ++k) {
        _Float16 hh = (_Float16)pv[k];
        h[k] = hh;
        l[k] = (_Float16)(pv[k] - (float)hh);
    }
    *(f16x4*)&wh[i] = h;
    *(f16x4*)&wl[i] = l;
}

// ---------- Kernel B: fused split-f16 MFMA GEMM + top-2 + softmax ----------
// 512 thr = 8 waves: w = kg*4 + tg*2 + eg. Wave: 32 tok x 32 exp x 1024 k.
__global__ __launch_bounds__(512) void router_kernel(const float* __restrict__ x,
                                                     const _Float16* __restrict__ wsp,
                                                     const float* __restrict__ b,
                                                     float* __restrict__ out) {
    __shared__ __align__(16) char lds[131072];

    const int tid  = threadIdx.x;
    const int w    = tid >> 6;
    const int lane = tid & 63;
    const int eg   = w & 1;
    const int tg   = (w >> 1) & 1;
    const int kg   = w >> 2;
    const int t0   = blockIdx.x * TB;

    // staging ids: x: 64 rows x 8 octets; W: 4 insts x flat(kg,spl,e,oct)
    const int xr = tid >> 3, xo = tid & 7;

    float4 xv[2][2];
    f16x8  wv[4];

    auto issue_loads = [&](int p) {
        #pragma unroll
        for (int g = 0; g < 2; ++g) {
            const float* src = x + (size_t)(t0 + xr) * DIM + g * HALFK + p * KPH + xo * 8;
            xv[g][0] = *(const float4*)src;
            xv[g][1] = *(const float4*)(src + 4);
        }
        #pragma unroll
        for (int q = 0; q < 4; ++q) {
            const int flat = q * 512 + tid;
            const int fkg = flat >> 10, fsp = (flat >> 9) & 1;
            const int fe = (flat >> 3) & 63, fo = flat & 7;
            wv[q] = *(const f16x8*)(wsp + (size_t)fsp * (NE * DIM) + fe * DIM
                                        + fkg * HALFK + p * KPH + fo * 8);
        }
    };
    auto write_stage = [&](int buf) {
        #pragma unroll
        for (int g = 0; g < 2; ++g) {
            f16x8 h, l;
            #pragma unroll
            for (int j = 0; j < 2; ++j) {
                const float* pv = (const float*)&xv[g][j];
                #pragma unroll
                for (int k = 0; k < 4; ++k) {
                    _Float16 hh = (_Float16)pv[k];
                    h[j * 4 + k] = hh;
                    l[j * 4 + k] = (_Float16)(pv[k] - (float)hh);
                }
            }
            char* xb = lds + buf * 65536 + (g * 2) * 8192 + xr * 128 + ((xo ^ sw(xr)) * 16);
            *(f16x8*)xb = h;
            *(f16x8*)(xb + 8192) = l;
        }
        #pragma unroll
        for (int q = 0; q < 4; ++q) {
            const int flat = q * 512 + tid;
            const int fkg = flat >> 10, fsp = (flat >> 9) & 1;
            const int fe = (flat >> 3) & 63, fo = flat & 7;
            *(f16x8*)(lds + buf * 65536 + 32768 + (fkg * 2 + fsp) * 8192
                          + fe * 128 + ((fo ^ sw(fe)) * 16)) = wv[q];
        }
    };

    // MFMA fragment ids: A row = token (tile row), B row = expert
    const int am = tg * 32 + (lane & 31);
    const int be = eg * 32 + (lane & 31);
    const int koct = lane >> 5;
    const int swa = sw(am), swb = sw(be);

    f32x16 acc;
    #pragma unroll
    for (int i = 0; i < 16; ++i) acc[i] = 0.0f;

    issue_loads(0);
    write_stage(0);
    __syncthreads();

    for (int p = 0; p < NPH; ++p) {
        const int buf = p & 1;
        if (p + 1 < NPH) issue_loads(p + 1);

        const char* xb = lds + buf * 65536 + kg * 16384;
        const char* wb = xb + 32768;
        #pragma unroll
        for (int s = 0; s < 4; ++s) {
            const int oa = ((s * 2 + koct) ^ swa) * 16;
            const int ob = ((s * 2 + koct) ^ swb) * 16;
            f16x8 ah = *(const f16x8*)(xb + am * 128 + oa);
            f16x8 al = *(const f16x8*)(xb + 8192 + am * 128 + oa);
            f16x8 bh = *(const f16x8*)(wb + be * 128 + ob);
            f16x8 bl = *(const f16x8*)(wb + 8192 + be * 128 + ob);
            acc = __builtin_amdgcn_mfma_f32_32x32x16_f16(ah, bh, acc, 0, 0, 0);
            acc = __builtin_amdgcn_mfma_f32_32x32x16_f16(ah, bl, acc, 0, 0, 0);
            acc = __builtin_amdgcn_mfma_f32_32x32x16_f16(al, bh, acc, 0, 0, 0);
        }

        if (p + 1 < NPH) write_stage(buf ^ 1);
        __syncthreads();
    }

    // ---- k-half reduce via LDS (buf0 is dead: last phase read buf1) ----
    float* redf = (float*)lds;                 // 64 x 64 f32 = 16 KB
    const int ccol = eg * 32 + (lane & 31);
    if (kg == 1) {
        #pragma unroll
        for (int r = 0; r < 16; ++r) {
            const int row = tg * 32 + (r & 3) + 8 * (r >> 2) + 4 * (lane >> 5);
            redf[row * 64 + ccol] = acc[r];
        }
    }
    __syncthreads();
    if (kg == 0) {
        const float bv = b[ccol];
        #pragma unroll
        for (int r = 0; r < 16; ++r) {
            const int row = tg * 32 + (r & 3) + 8 * (r >> 2) + 4 * (lane >> 5);
            redf[row * 64 + ccol] += acc[r] + bv;
        }
    }
    __syncthreads();

    // ---- logits to global (coalesced) ----
    float* logits_out = out + (size_t)TOKENS * 4;
    {
        const float4* rsrc = (const float4*)redf;
        float4 v0 = rsrc[tid * 2];
        float4 v1 = rsrc[tid * 2 + 1];
        *(float4*)&logits_out[(size_t)t0 * 64 + tid * 8]     = v0;
        *(float4*)&logits_out[(size_t)t0 * 64 + tid * 8 + 4] = v1;
    }

    // ---- top-2 + softmax: wave w handles tokens w*8 .. w*8+7 ----
    float* idxf = out + (size_t)TOKENS * 2;
    for (int i = 0; i < 8; ++i) {
        const int t = w * 8 + i;
        const float v = redf[t * 64 + lane];

        float v1 = v; int i1 = lane;
        #pragma unroll
        for (int off = 32; off >= 1; off >>= 1) {
            float ov = __shfl_xor(v1, off, 64);
            int   oi = __shfl_xor(i1, off, 64);
            if (ov > v1 || (ov == v1 && oi < i1)) { v1 = ov; i1 = oi; }
        }
        float vm = (lane == i1) ? -INFINITY : v;
        float v2 = vm; int i2 = lane;
        #pragma unroll
        for (int off = 32; off >= 1; off >>= 1) {
            float ov = __shfl_xor(v2, off, 64);
            int   oi = __shfl_xor(i2, off, 64);
            if (ov > v2 || (ov == v2 && oi < i2)) { v2 = ov; i2 = oi; }
        }

        if (lane == 0) {
            const int tok = t0 + t;
            float e1 = expf(v2 - v1);
            float sden = 1.0f + e1;
            *(float2*)&out[(size_t)tok * 2]  = make_float2(1.0f / sden, e1 / sden);
            *(float2*)&idxf[(size_t)tok * 2] = make_float2((float)i1, (float)i2);
        }
    }
}

extern "C" void kernel_launch(void* const* d_in, const int* in_sizes, int n_in,
                              void* d_out, int out_size, void* d_ws, size_t ws_size,
                              hipStream_t stream) {
    const float* x = (const float*)d_in[0];
    const float* W = (const float*)d_in[1];
    const float* b = (const float*)d_in[2];
    float* out = (float*)d_out;

    _Float16* wh = (_Float16*)d_ws;            // [64][2048] f16 hi
    _Float16* wl = wh + NE * DIM;              // [64][2048] f16 lo  (512 KB total)

    wsplit_kernel<<<(NE * DIM) / (256 * 4), 256, 0, stream>>>(W, wh, wl);
    router_kernel<<<TOKENS / TB, 512, 0, stream>>>(x, (const _Float16*)d_ws, b, out);
}

// Round 6
// 211.491 us; speedup vs baseline: 1.4727x; 1.0276x over previous
//
#include <hip/hip_runtime.h>
#include <math.h>

#define TOKENS 16384
#define DIM    2048
#define NE     64
#define TB     32            // tokens per block (one 32-row MFMA tile)
#define KG     4             // k-split across the block's 4 waves
#define KW     (DIM / KG)    // 512 k per wave
#define NCH    (KW / 16)     // 32 chunks of 16 k

typedef _Float16 f16x8 __attribute__((ext_vector_type(8)));
typedef float    f32x16 __attribute__((ext_vector_type(16)));

// ---------- Kernel A: pack W fp32 -> split-f16 B-fragment layout ----------
// wp layout (f16 units): ((c*2 + eg)*2 + hl)*512 + lane*8 + j
//   c   = k-chunk (16 k), 0..127      eg = expert half (32 experts)
//   hl  = 0 hi / 1 lo residual        lane: e = eg*32+(lane&31), k = c*16+(lane>>5)*8+j
__global__ __launch_bounds__(256) void wpack_kernel(const float* __restrict__ W,
                                                    _Float16* __restrict__ wp) {
    const int g  = blockIdx.x * 256 + threadIdx.x;   // 16384 threads
    const int c  = g >> 7;
    const int eg = (g >> 6) & 1;
    const int l  = g & 63;
    const int e  = eg * 32 + (l & 31);
    const int k0 = c * 16 + (l >> 5) * 8;
    const float* src = W + (size_t)e * DIM + k0;
    float4 a = *(const float4*)src;
    float4 bq = *(const float4*)(src + 4);
    const float* pa = (const float*)&a;
    const float* pb = (const float*)&bq;
    f16x8 h, lo;
    #pragma unroll
    for (int j = 0; j < 4; ++j) {
        _Float16 h1 = (_Float16)pa[j];
        h[j] = h1; lo[j] = (_Float16)(pa[j] - (float)h1);
        _Float16 h2 = (_Float16)pb[j];
        h[4 + j] = h2; lo[4 + j] = (_Float16)(pb[j] - (float)h2);
    }
    _Float16* dst = wp + ((size_t)(c * 2 + eg) * 2) * 512 + l * 8;
    *(f16x8*)dst = h;
    *(f16x8*)(dst + 512) = lo;
}

// ---------- Kernel B: barrier-free split-f16 MFMA GEMM + top-2 + softmax ----------
// 256 thr = 4 waves, wave = kg. Wave computes 32 tok x 64 exp over its 512-k slice,
// A-frags straight from global x, B-frags from packed wp. One barrier at epilogue.
__global__ __launch_bounds__(256) void router_kernel(const float* __restrict__ x,
                                                     const _Float16* __restrict__ wp,
                                                     const float* __restrict__ b,
                                                     float* __restrict__ out) {
    __shared__ __align__(16) float lds[KG * TB * NE];   // 32 KB: 4 partial zones

    const int tid  = threadIdx.x;
    const int kg   = tid >> 6;
    const int lane = tid & 63;
    const int t0   = blockIdx.x * TB;
    const int m    = lane & 31;        // token row within tile
    const int ko   = lane >> 5;        // k-octet half

    const float* xp = x + (size_t)(t0 + m) * DIM + kg * KW + ko * 8;
    const _Float16* wpb = wp + (size_t)kg * NCH * 2048;   // chunk stride = 2048 f16

    f32x16 acc0, acc1;
    #pragma unroll
    for (int i = 0; i < 16; ++i) { acc0[i] = 0.0f; acc1[i] = 0.0f; }

    float4 xs0[2], xs1[2];
    f16x8  bs[2][4];

    auto ld = [&](int c, int sl) {
        const float* s = xp + c * 16;
        xs0[sl] = *(const float4*)s;
        xs1[sl] = *(const float4*)(s + 4);
        const _Float16* wb = wpb + (size_t)c * 2048 + lane * 8;
        bs[sl][0] = *(const f16x8*)(wb);           // eg0 hi
        bs[sl][1] = *(const f16x8*)(wb + 512);     // eg0 lo
        bs[sl][2] = *(const f16x8*)(wb + 1024);    // eg1 hi
        bs[sl][3] = *(const f16x8*)(wb + 1536);    // eg1 lo
    };

    ld(0, 0);
    ld(1, 1);

    #pragma unroll 2
    for (int c = 0; c < NCH; ++c) {
        const int sl = c & 1;
        f16x8 ah, al;
        {
            const float* p0 = (const float*)&xs0[sl];
            const float* p1 = (const float*)&xs1[sl];
            #pragma unroll
            for (int j = 0; j < 4; ++j) {
                _Float16 h1 = (_Float16)p0[j];
                ah[j] = h1; al[j] = (_Float16)(p0[j] - (float)h1);
                _Float16 h2 = (_Float16)p1[j];
                ah[4 + j] = h2; al[4 + j] = (_Float16)(p1[j] - (float)h2);
            }
        }
        const f16x8 b0h = bs[sl][0], b0l = bs[sl][1];
        const f16x8 b1h = bs[sl][2], b1l = bs[sl][3];

        acc0 = __builtin_amdgcn_mfma_f32_32x32x16_f16(ah, b0h, acc0, 0, 0, 0);
        acc1 = __builtin_amdgcn_mfma_f32_32x32x16_f16(ah, b1h, acc1, 0, 0, 0);
        acc0 = __builtin_amdgcn_mfma_f32_32x32x16_f16(ah, b0l, acc0, 0, 0, 0);
        acc1 = __builtin_amdgcn_mfma_f32_32x32x16_f16(ah, b1l, acc1, 0, 0, 0);
        acc0 = __builtin_amdgcn_mfma_f32_32x32x16_f16(al, b0h, acc0, 0, 0, 0);
        acc1 = __builtin_amdgcn_mfma_f32_32x32x16_f16(al, b1h, acc1, 0, 0, 0);

        if (c + 2 < NCH) ld(c + 2, sl);
    }

    // ---- partials -> LDS zone kg (row-major 32 x 64) ----
    float* zone = lds + kg * (TB * NE);
    #pragma unroll
    for (int r = 0; r < 16; ++r) {
        const int row = (r & 3) + 8 * (r >> 2) + 4 * ko;   // C/D layout (verified)
        zone[row * 64 + m]      = acc0[r];
        zone[row * 64 + 32 + m] = acc1[r];
    }
    __syncthreads();

    // ---- block-wide reduce of 4 zones + bias; logits to global; stage for top-2 ----
    float* logits_out = out + (size_t)TOKENS * 4;
    {
        const int row = tid >> 3;          // 0..31
        const int c8  = (tid & 7) * 8;     // col start
        const int base = row * 64 + c8;
        float4 s0 = *(float4*)&lds[base];
        float4 s1 = *(float4*)&lds[base + 4];
        #pragma unroll
        for (int z = 1; z < KG; ++z) {
            float4 a0 = *(float4*)&lds[z * 2048 + base];
            float4 a1 = *(float4*)&lds[z * 2048 + base + 4];
            s0.x += a0.x; s0.y += a0.y; s0.z += a0.z; s0.w += a0.w;
            s1.x += a1.x; s1.y += a1.y; s1.z += a1.z; s1.w += a1.w;
        }
        float4 bv0 = *(const float4*)&b[c8];
        float4 bv1 = *(const float4*)&b[c8 + 4];
        s0.x += bv0.x; s0.y += bv0.y; s0.z += bv0.z; s0.w += bv0.w;
        s1.x += bv1.x; s1.y += bv1.y; s1.z += bv1.z; s1.w += bv1.w;
        *(float4*)&lds[base]     = s0;     // zone0 in-place (safe: same thread's slot)
        *(float4*)&lds[base + 4] = s1;
        *(float4*)&logits_out[(size_t)(t0 + row) * 64 + c8]     = s0;
        *(float4*)&logits_out[(size_t)(t0 + row) * 64 + c8 + 4] = s1;
    }
    __syncthreads();

    // ---- top-2 + softmax: wave kg handles tokens kg*8 .. kg*8+7 ----
    float* idxf = out + (size_t)TOKENS * 2;
    for (int i = 0; i < 8; ++i) {
        const int t = kg * 8 + i;
        const float v = lds[t * 64 + lane];

        float v1 = v; int i1 = lane;
        #pragma unroll
        for (int off = 32; off >= 1; off >>= 1) {
            float ov = __shfl_xor(v1, off, 64);
            int   oi = __shfl_xor(i1, off, 64);
            if (ov > v1 || (ov == v1 && oi < i1)) { v1 = ov; i1 = oi; }
        }
        float vm = (lane == i1) ? -INFINITY : v;
        float v2 = vm; int i2 = lane;
        #pragma unroll
        for (int off = 32; off >= 1; off >>= 1) {
            float ov = __shfl_xor(v2, off, 64);
            int   oi = __shfl_xor(i2, off, 64);
            if (ov > v2 || (ov == v2 && oi < i2)) { v2 = ov; i2 = oi; }
        }

        if (lane == 0) {
            const int tok = t0 + t;
            float e1 = expf(v2 - v1);          // v1 >= v2: stable
            float sden = 1.0f + e1;
            *(float2*)&out[(size_t)tok * 2]  = make_float2(1.0f / sden, e1 / sden);
            *(float2*)&idxf[(size_t)tok * 2] = make_float2((float)i1, (float)i2);
        }
    }
}

extern "C" void kernel_launch(void* const* d_in, const int* in_sizes, int n_in,
                              void* d_out, int out_size, void* d_ws, size_t ws_size,
                              hipStream_t stream) {
    const float* x = (const float*)d_in[0];
    const float* W = (const float*)d_in[1];
    const float* b = (const float*)d_in[2];
    float* out = (float*)d_out;
    _Float16* wp = (_Float16*)d_ws;    // 128*2*2*512 f16 = 512 KB packed fragments

    wpack_kernel<<<64, 256, 0, stream>>>(W, wp);
    router_kernel<<<TOKENS / TB, 256, 0, stream>>>(x, wp, b, out);
}